// Round 4
// baseline (364.580 us; speedup 1.0000x reference)
//
#include <hip/hip_runtime.h>

// Problem constants (match reference)
#define N_NODES 8192
#define E_EDGES 262144
#define EPS_F   1e-8f

// Bucketing: one bucket per adjacency row (src). Pos buckets [0,8192),
// neg buckets [8192,16384). Gather blocks each own 4 consecutive rows.
#define NBUCK      16384
#define GATHER_BLK 2048            // blocks; block b owns rows [4b,4b+4)

// ws layout (bytes) — ws is >= 1 GiB, poisoned 0xAA each call.
#define WS_COUNTS   0              // u32[16384]
#define WS_OFFSETS  65536          // u32[16385]
#define WS_CURSOR   262144         // u32[16384]
#define WS_RECS     524288         // u32[524288]  packed (src<<13)|dst
#define WS_PARTIALS 4194304        // float[4096]  pos [0,2048), neg [2048,4096)

// K0: zero the bucket counters (ws is poisoned, not zeroed).
__global__ __launch_bounds__(256) void zero_counts_kernel(unsigned* __restrict__ counts)
{
    const int i = blockIdx.x * 256 + threadIdx.x;
    if (i < NBUCK) counts[i] = 0u;
}

// K1: histogram edges into per-row buckets.
__global__ __launch_bounds__(256) void hist_kernel(
    const int* __restrict__ edge_index,   // [2][E]
    const int* __restrict__ neg_edges,    // [E][2]
    unsigned*  __restrict__ counts)
{
    const int i = blockIdx.x * 256 + threadIdx.x;   // [0, E)
    const int src = edge_index[i];
    atomicAdd(&counts[src], 1u);
    const int2 np = ((const int2*)neg_edges)[i];
    atomicAdd(&counts[8192 + np.x], 1u);
}

// K2: exclusive prefix scan over 16384 counters (1 block, 1024 threads,
// 16 elements/thread). Writes offsets[16385] and cursor copy.
__global__ __launch_bounds__(1024) void scan_kernel(
    const unsigned* __restrict__ counts,
    unsigned*       __restrict__ offsets,
    unsigned*       __restrict__ cursor)
{
    const int t = threadIdx.x;
    const int base = t * 16;
    unsigned local[16];
    unsigned run = 0;
    #pragma unroll
    for (int k = 0; k < 16; ++k) { local[k] = counts[base + k]; run += local[k]; }

    __shared__ unsigned s_sum[1024];
    s_sum[t] = run;
    __syncthreads();
    // Hillis–Steele inclusive scan (read-all-then-write, double sync)
    for (int off = 1; off < 1024; off <<= 1) {
        unsigned v = 0;
        if (t >= off) v = s_sum[t - off];
        __syncthreads();
        if (t >= off) s_sum[t] += v;
        __syncthreads();
    }
    unsigned excl = (t == 0) ? 0u : s_sum[t - 1];
    #pragma unroll
    for (int k = 0; k < 16; ++k) {
        offsets[base + k] = excl;
        cursor[base + k]  = excl;
        excl += local[k];
    }
    if (t == 1023) offsets[NBUCK] = excl;   // == 2E
}

// K3: scatter packed edge records into bucket-sorted order.
__global__ __launch_bounds__(256) void scatter_kernel(
    const int* __restrict__ edge_index,
    const int* __restrict__ neg_edges,
    unsigned*  __restrict__ cursor,
    unsigned*  __restrict__ recs)
{
    const int i = blockIdx.x * 256 + threadIdx.x;   // [0, E)
    {
        const int src = edge_index[i];
        const int dst = edge_index[E_EDGES + i];
        const unsigned idx = atomicAdd(&cursor[src], 1u);
        recs[idx] = ((unsigned)src << 13) | (unsigned)dst;
    }
    {
        const int2 np = ((const int2*)neg_edges)[i];
        const unsigned idx = atomicAdd(&cursor[8192 + np.x], 1u);
        recs[idx] = ((unsigned)np.x << 13) | (unsigned)np.y;
    }
}

// K4: locality-ordered gather + log + block reduction.
// Block b: pos rows [4b,4b+4) via offsets[4b..4b+4],
//          neg rows via offsets[8192+4b .. 8192+4b+4].
__global__ __launch_bounds__(256) void gather_kernel(
    const float*    __restrict__ adj,
    const unsigned* __restrict__ offsets,
    const unsigned* __restrict__ recs,
    float*          __restrict__ partials)
{
    const int b   = blockIdx.x;
    const int t   = threadIdx.x;
    const int lid = t & 63;
    const int wid = t >> 6;

    float accP = 0.f, accN = 0.f;
    {
        const unsigned lo = offsets[4 * b];
        const unsigned hi = offsets[4 * b + 4];
        for (unsigned j = lo + t; j < hi; j += 256) {
            const unsigned r = recs[j];
            const float p = adj[(size_t)(r >> 13) * N_NODES + (size_t)(r & 8191u)];
            accP += logf(p + EPS_F);
        }
    }
    {
        const unsigned lo = offsets[8192 + 4 * b];
        const unsigned hi = offsets[8192 + 4 * b + 4];
        for (unsigned j = lo + t; j < hi; j += 256) {
            const unsigned r = recs[j];
            const float p = adj[(size_t)(r >> 13) * N_NODES + (size_t)(r & 8191u)];
            accN += logf(1.0f - p + EPS_F);
        }
    }

    #pragma unroll
    for (int off = 32; off > 0; off >>= 1) {
        accP += __shfl_down(accP, off, 64);
        accN += __shfl_down(accN, off, 64);
    }
    __shared__ float s_p[4];
    __shared__ float s_n[4];
    if (lid == 0) { s_p[wid] = accP; s_n[wid] = accN; }
    __syncthreads();
    if (t == 0) {
        float tp = 0.f, tn = 0.f;
        #pragma unroll
        for (int w = 0; w < 4; ++w) { tp += s_p[w]; tn += s_n[w]; }
        partials[b]              = tp;
        partials[GATHER_BLK + b] = tn;
    }
}

// K5: final reduction + codebook terms.
__global__ __launch_bounds__(1024) void finalize_kernel(
    const float* __restrict__ partials,
    const float* __restrict__ codebook,
    float*       __restrict__ out)
{
    const int t   = threadIdx.x;
    const int lid = t & 63;
    const int wid = t >> 6;

    float lp = partials[t] + partials[t + 1024];
    float ln = partials[2048 + t] + partials[3072 + t];

    #pragma unroll
    for (int off = 32; off > 0; off >>= 1) {
        lp += __shfl_down(lp, off, 64);
        ln += __shfl_down(ln, off, 64);
    }
    __shared__ float s_lp[16];
    __shared__ float s_ln[16];
    if (lid == 0) { s_lp[wid] = lp; s_ln[wid] = ln; }
    __syncthreads();
    if (t == 0) {
        float tlp = 0.f, tln = 0.f;
        #pragma unroll
        for (int w = 0; w < 16; ++w) { tlp += s_lp[w]; tln += s_ln[w]; }
        const float pos_loss = -tlp / (float)E_EDGES;
        const float neg_loss = -tln / (float)E_EDGES;
        const float rec_loss = pos_loss + neg_loss;          // REC_WEIGHT = 1.0
        out[0] = rec_loss + codebook[0] + codebook[1] + codebook[2] + codebook[3];
    }
}

extern "C" void kernel_launch(void* const* d_in, const int* in_sizes, int n_in,
                              void* d_out, int out_size, void* d_ws, size_t ws_size,
                              hipStream_t stream)
{
    const float* adj       = (const float*)d_in[0];
    const float* codebook  = (const float*)d_in[1];
    const int*   edge_idx  = (const int*)d_in[2];
    const int*   neg_edges = (const int*)d_in[3];
    float*       out       = (float*)d_out;

    char* ws = (char*)d_ws;
    unsigned* counts   = (unsigned*)(ws + WS_COUNTS);
    unsigned* offsets  = (unsigned*)(ws + WS_OFFSETS);
    unsigned* cursor   = (unsigned*)(ws + WS_CURSOR);
    unsigned* recs     = (unsigned*)(ws + WS_RECS);
    float*    partials = (float*)   (ws + WS_PARTIALS);

    zero_counts_kernel<<<NBUCK / 256, 256, 0, stream>>>(counts);
    hist_kernel<<<E_EDGES / 256, 256, 0, stream>>>(edge_idx, neg_edges, counts);
    scan_kernel<<<1, 1024, 0, stream>>>(counts, offsets, cursor);
    scatter_kernel<<<E_EDGES / 256, 256, 0, stream>>>(edge_idx, neg_edges, cursor, recs);
    gather_kernel<<<GATHER_BLK, 256, 0, stream>>>(adj, offsets, recs, partials);
    finalize_kernel<<<1, 1024, 0, stream>>>(partials, codebook, out);
}